// Round 6
// baseline (1998.634 us; speedup 1.0000x reference)
//
#include <hip/hip_runtime.h>
#include <math.h>

#define BB 32
#define HH_ 128
#define WW_ 256

typedef _Float16 f16_t;
typedef _Float16 half8 __attribute__((ext_vector_type(8)));
typedef float floatx4 __attribute__((ext_vector_type(4)));

// Branch-free gelu: Abramowitz-Stegun 7.1.26 erf (|eps|<=1.5e-7), hw exp2+rcp.
__device__ __forceinline__ float gelu_f(float v){
  float z  = v * 0.70710678118654752f;
  float az = __builtin_fabsf(z);
  float t  = __builtin_amdgcn_rcpf(__builtin_fmaf(0.3275911f, az, 1.0f));
  float p  = __builtin_fmaf(1.061405429f, t, -1.453152027f);
  p = __builtin_fmaf(p, t, 1.421413741f);
  p = __builtin_fmaf(p, t, -0.284496736f);
  p = __builtin_fmaf(p, t, 0.254829592f);
  p = p * t;
  float e  = exp2f(-az*az*1.44269504088896f);
  float er = __builtin_copysignf(__builtin_fmaf(-p, e, 1.0f), z);
  return 0.5f*v*(1.0f + er);
}

__global__ void k_diag(float* out, float v){ out[threadIdx.x] = v; }

// ---------------- twiddle tables -------------------------------------------
__global__ void k_tables(float2* twf, float2* thf, float2* thi, f16_t* twzh){
  int t = blockIdx.x*256 + threadIdx.x;
  const double PI2 = 6.283185307179586476925286766559;
  if (t < 3072){                       // forward w-DFT: [w][ky]
    int w = t/12, ky = t%12;
    double a = -PI2 * (double)(w*ky) / 256.0;
    twf[t] = make_float2((float)cos(a), (float)sin(a));
  } else if (t < 6144){                // forward h-DFT: [h][j], kx {0..11,116..127}
    int f = t-3072; int h = f/24, j = f%24;
    int kx = (j<12)? j : j+104;
    double a = -PI2 * (double)(h*kx) / 128.0;
    thf[f] = make_float2((float)cos(a), (float)sin(a));
  } else if (t < 9216){                // inverse h (includes 1/128)
    int f = t-6144; int h = f/24, j = f%24;
    int kx = (j<12)? j : j+104;
    double a = PI2 * (double)(h*kx) / 128.0;
    thi[f] = make_float2((float)(cos(a)/128.0), (float)(sin(a)/128.0));
  } else if (t < 12288){               // inverse w (c2r) coefs, f16, [w][32]
    int f = t-9216; int w = f/12, ky = f%12;
    double a = PI2 * (double)(w*ky) / 256.0;
    double s = (ky==0)? 1.0 : 2.0;
    twzh[w*32 + ky]      = (f16_t)( s*cos(a)/256.0);
    twzh[w*32 + 12 + ky] = (f16_t)(-s*sin(a)/256.0);
    if (ky < 8) twzh[w*32 + 24 + ky] = (f16_t)0.f;
  }
}

// ---------------- conv weight transpose: wT[t][tap][o][c] f16 ----------------
__global__ __launch_bounds__(256) void k_wprep(const float* __restrict__ tw,
                                               f16_t* __restrict__ wT){
  int t = blockIdx.x*256 + threadIdx.x;     // < 14*9*64*64 = 516096
  int c = t & 63, o = (t >> 6) & 63, r = t >> 12;
  int tap = r % 9, tt = r / 9;
  wT[t] = (f16_t)tw[(((tt*64 + o)*64 + c)*9) + tap];
}

// ---------------- head weights -> f16 ---------------------------------------
__global__ __launch_bounds__(256) void k_wprep2(const float* __restrict__ f1_w,
      const float* __restrict__ f2_w, const float* __restrict__ f3_w,
      f16_t* __restrict__ f1T, f16_t* __restrict__ f2T, f16_t* __restrict__ f3T){
  int t = blockIdx.x*256 + threadIdx.x;
  if (t < 8192) f1T[t] = (f16_t)f1_w[t];
  else if (t < 16384) f2T[t-8192] = (f16_t)f2_w[t-8192];
  else if (t < 16512) f3T[t-16384] = (f16_t)f3_w[t-16384];
}

// -------- spectral weight transpose: wmix[l][j][ky][i*64+o] float2 ----------
__global__ __launch_bounds__(256) void k_mixprep(const float* __restrict__ w1r,
      const float* __restrict__ w1i, const float* __restrict__ w2r,
      const float* __restrict__ w2i, float2* __restrict__ wmix){
  long t = (long)blockIdx.x*256 + threadIdx.x;   // < 4*24*12*4096
  int io = (int)(t & 4095);
  int r  = (int)(t >> 12);
  int ky = r % 12; int r2 = r / 12;
  int j  = r2 % 24; int l = r2 / 24;
  int i = io >> 6, o = io & 63;
  const float* wr; const float* wi; int kx;
  if (j < 12){ wr = w1r; wi = w1i; kx = j; } else { wr = w2r; wi = w2i; kx = j - 12; }
  long src = (((long)l*64 + i)*64 + o)*144 + kx*12 + ky;
  wmix[t] = make_float2(wr[src], wi[src]);
}

// ---------------- ext -> g1 (B x 64) ----------------------------------------
__global__ void k_ext(const float* __restrict__ ext, const float* __restrict__ day_emb,
                      const float* __restrict__ hour_emb, const float* __restrict__ e1_w,
                      const float* __restrict__ e1_b, float* __restrict__ g1){
  int b = blockIdx.x, j = threadIdx.x;
  const float* e = ext + b*6;
  float emb[6];
  emb[0] = e[0];
  int d  = (int)e[2];
  emb[1] = day_emb[d*2];  emb[2] = day_emb[d*2+1];
  int hr = (int)e[3];
  emb[3] = hour_emb[hr*3]; emb[4] = hour_emb[hr*3+1]; emb[5] = hour_emb[hr*3+2];
  float acc = e1_b[j];
  #pragma unroll
  for (int k = 0; k < 6; k++) acc += emb[k]*e1_w[j*6+k];
  g1[b*64 + j] = gelu_f(acc);
}

// ---------------- g1 -> g (B x HW) ------------------------------------------
__global__ __launch_bounds__(256) void k_g(const float* __restrict__ g1,
      const float* __restrict__ e2_w, const float* __restrict__ e2_b, float* __restrict__ g){
  int b = blockIdx.y;
  int hw = blockIdx.x*256 + threadIdx.x;
  __shared__ float s[64];
  if (threadIdx.x < 64) s[threadIdx.x] = g1[b*64 + threadIdx.x];
  __syncthreads();
  const float4* wrow = (const float4*)(e2_w + (long)hw*64);
  float acc = e2_b[hw];
  #pragma unroll
  for (int k = 0; k < 16; k++){
    float4 v = wrow[k];
    acc += v.x*s[4*k] + v.y*s[4*k+1] + v.z*s[4*k+2] + v.w*s[4*k+3];
  }
  g[(long)b*(HH_*WW_) + hw] = gelu_f(acc);
}

// ---------------- encoder: x[b,h,w,c] f16 -----------------------------------
__global__ __launch_bounds__(256) void k_enc(const float* __restrict__ inp,
      const float* __restrict__ g, const float* __restrict__ enc_w,
      const float* __restrict__ enc_b, f16_t* __restrict__ x){
  long t = (long)blockIdx.x*256 + threadIdx.x;   // < B*HW*64
  int c = (int)(t & 63);
  long pix = t >> 6;
  const float* ip = inp + pix*4;
  const float* wr = enc_w + c*5;
  float acc = enc_b[c] + ip[0]*wr[0] + ip[1]*wr[1] + ip[2]*wr[2] + ip[3]*wr[3] + g[pix]*wr[4];
  x[t] = (f16_t)acc;
}

// ---------------- forward DFT along w (layer 0 only): fft1p0 ----------------
__global__ __launch_bounds__(256) void k_dft_w(const f16_t* __restrict__ x,
      const float4* __restrict__ twf4, float2* __restrict__ fft1){
  __shared__ float4 tw[1536];                      // [w][6]
  for (int f = threadIdx.x; f < 1536; f += 256) tw[f] = twf4[f];
  __syncthreads();
  int wave = threadIdx.x >> 6, lane = threadIdx.x & 63;
  long row = (long)blockIdx.x*4 + wave;            // b*H + h
  const f16_t* xr = x + row*16384 + lane;
  float ar[12], ai[12];
  #pragma unroll
  for (int k = 0; k < 12; k++){ ar[k] = 0.f; ai[k] = 0.f; }
  for (int w = 0; w < 256; w++){
    float xv = (float)xr[(long)w*64];
    const float4* t = &tw[w*6];
    #pragma unroll
    for (int k = 0; k < 6; k++){
      float4 tv = t[k];
      ar[2*k]   += xv*tv.x;  ai[2*k]   += xv*tv.y;
      ar[2*k+1] += xv*tv.z;  ai[2*k+1] += xv*tv.w;
    }
  }
  float2* op = fft1 + row*768 + lane;
  #pragma unroll
  for (int ky = 0; ky < 12; ky++) op[ky*64] = make_float2(ar[ky], ai[ky]);
}

// ------- forward DFT along h, tiled: block=(b,ky); sums split halves --------
__global__ __launch_bounds__(256) void k_dft_h(const float2* __restrict__ s0,
      const float2* __restrict__ s1, int dual,
      const float2* __restrict__ thf, float2* __restrict__ xft){
  __shared__ float2 th[3072];                      // [h][24]
  __shared__ float2 xch[2048];                     // [32 h][64 c]
  int tid = threadIdx.x;
  for (int f = tid; f < 3072; f += 256) th[f] = thf[f];
  int b = blockIdx.x / 12, ky = blockIdx.x % 12;
  int wv = tid >> 6, lane = tid & 63;
  float2 acc[6];
  #pragma unroll
  for (int q = 0; q < 6; q++) acc[q] = make_float2(0.f, 0.f);
  long base = (long)b*98304 + ky*64;
  for (int ch = 0; ch < 4; ch++){
    __syncthreads();
    for (int f = tid; f < 2048; f += 256){
      int hh = f >> 6, c = f & 63;
      long idx = base + (long)(ch*32 + hh)*768 + c;
      float2 v = s0[idx];
      if (dual){ float2 u = s1[idx]; v.x += u.x; v.y += u.y; }
      xch[f] = v;
    }
    __syncthreads();
    for (int hh = 0; hh < 32; hh++){
      float2 v = xch[hh*64 + lane];
      int hg = ch*32 + hh;
      #pragma unroll
      for (int q = 0; q < 6; q++){
        float2 t = th[hg*24 + q*4 + wv];
        acc[q].x += t.x*v.x - t.y*v.y;
        acc[q].y += t.x*v.y + t.y*v.x;
      }
    }
  }
  #pragma unroll
  for (int q = 0; q < 6; q++){
    int j = q*4 + wv;
    xft[((long)b*288 + j*12 + ky)*64 + lane] = acc[q];
  }
}

// -------- mode mixing IN PLACE (coalesced weights from wmix) ----------------
__global__ __launch_bounds__(256) void k_mix(const float2* __restrict__ wmix,
      int layer, float2* __restrict__ xft){
  __shared__ float2 wl[4096];                      // [i][o]
  int jk = blockIdx.x >> 1;
  int bh2 = blockIdx.x & 1;
  int j = jk / 12, ky = jk % 12;
  const float2* wsrc = wmix + ((long)layer*288 + jk)*4096;
  for (int f = threadIdx.x; f < 4096; f += 256) wl[f] = wsrc[f];
  __syncthreads();
  int wave = threadIdx.x >> 6, lane = threadIdx.x & 63;
  for (int b = bh2*16 + wave; b < bh2*16 + 16; b += 4){
    long base = ((long)b*288 + j*12 + ky)*64;
    float2 mine = xft[base + lane];
    float re = 0.f, im = 0.f;
    #pragma unroll 8
    for (int i = 0; i < 64; i++){
      float vr = __shfl(mine.x, i);
      float vi = __shfl(mine.y, i);
      float2 ww = wl[i*64 + lane];
      re += vr*ww.x - vi*ww.y;
      im += vr*ww.y + vi*ww.x;
    }
    xft[base + lane] = make_float2(re, im);
  }
}

// ------- inverse DFT along h, tiled: block=(b,ky), zi[b,h,ky,o] -------------
__global__ __launch_bounds__(256) void k_ifft_h(const float2* __restrict__ c3,
      const float2* __restrict__ thi, float2* __restrict__ zi){
  __shared__ float2 th[3072];                      // [h][24]
  int tid = threadIdx.x;
  for (int f = tid; f < 3072; f += 256) th[f] = thi[f];
  int b = blockIdx.x / 12, ky = blockIdx.x % 12;
  int wv = tid >> 6, lane = tid & 63;
  float2 cr[24];
  const float2* src = c3 + (long)b*18432 + ky*64 + lane;
  #pragma unroll
  for (int j = 0; j < 24; j++) cr[j] = src[(long)j*768];
  __syncthreads();
  for (int q = 0; q < 32; q++){
    int h = q*4 + wv;
    float re = 0.f, im = 0.f;
    #pragma unroll
    for (int j = 0; j < 24; j++){
      float2 t = th[h*24 + j];
      re += t.x*cr[j].x - t.y*cr[j].y;
      im += t.x*cr[j].y + t.y*cr[j].x;
    }
    zi[((long)b*128 + h)*768 + ky*64 + lane] = make_float2(re, im);
  }
}

// ------- MFMA: inverse-w + skip + bias + (gelu), in place on x,
//         fused with NEXT layer's partial w-DFT (written to fft1p0/p1) -------
__global__ __launch_bounds__(256) void k_iw_mfma(f16_t* __restrict__ x,
      const float2* __restrict__ zi, const float* __restrict__ ws_w,
      const float* __restrict__ ws_b, const f16_t* __restrict__ twzh,
      const float4* __restrict__ twf4g, float2* __restrict__ fft1p0,
      float2* __restrict__ fft1p1, int layer, int act, int dodft){
  __shared__ __align__(16) char sm[52736];
  f16_t* A  = (f16_t*)sm;                   // [128][136]; reused as Ob [128][72]
  f16_t* Bm = (f16_t*)(sm + 34816);         // [64][136]
  float* sb = (float*)(sm + 52224);         // [64]
  f16_t* Ob = (f16_t*)sm;
  float2* ps01 = (float2*)(sm + 18432);     // DFT partials, waves 0-1 (12 KB)
  float2* ps23 = (float2*)(sm + 34816);     // DFT partials, waves 2-3 (12 KB)
  int tid = threadIdx.x;
  int blk = blockIdx.x;
  int half = blk & 1;
  long bh = blk >> 1;                       // b*128 + h
  int w0 = half*128;
  const f16_t* xrow = x + (bh*256 + w0)*64;
  for (int f = tid; f < 1024; f += 256){    // x part, 16B copies
    int px = f >> 3, c8 = (f & 7)*8;
    *(float4*)((char*)A + (px*136 + c8)*2) = *(const float4*)(xrow + px*64 + c8);
  }
  for (int f = tid; f < 3072; f += 256){    // twz part (duplicated hi/lo)
    int px = f/24, k = f%24;
    f16_t v = twzh[(w0+px)*32 + k];
    A[px*136 + 64 + k] = v;
    A[px*136 + 88 + k] = v;
  }
  for (int f = tid; f < 3072; f += 256){    // A zero pad k=112..135
    int px = f/24, k = f%24;
    A[px*136 + 112 + k] = (f16_t)0.f;
  }
  const float* wsl = ws_w + (long)layer*4096;
  for (int f = tid; f < 1024; f += 256){    // B ws part
    int o = f >> 4, c4 = f & 15;
    float4 v = *(const float4*)(wsl + o*64 + c4*4);
    f16_t* d = Bm + o*136 + c4*4;
    d[0]=(f16_t)v.x; d[1]=(f16_t)v.y; d[2]=(f16_t)v.z; d[3]=(f16_t)v.w;
  }
  const float2* zrow = zi + bh*768;
  for (int f = tid; f < 768; f += 256){     // B z hi/lo
    int o = f & 63, ky = f >> 6;
    float2 v = zrow[ky*64 + o];
    f16_t hr = (f16_t)v.x; f16_t hi_ = (f16_t)v.y;
    Bm[o*136 + 64 + ky] = hr;
    Bm[o*136 + 76 + ky] = hi_;
    Bm[o*136 + 88 + ky] = (f16_t)(v.x - (float)hr);
    Bm[o*136 +100 + ky] = (f16_t)(v.y - (float)hi_);
  }
  for (int f = tid; f < 1536; f += 256){    // B zero pad
    int o = f/24, k = f%24;
    Bm[o*136 + 112 + k] = (f16_t)0.f;
  }
  if (tid < 64) sb[tid] = ws_b[layer*64 + tid];
  __syncthreads();
  int lane = tid & 63, wv = tid >> 6;
  int n15 = lane & 15, quad = lane >> 4;
  int n = wv*16 + n15;
  half8 bfr[4];
  #pragma unroll
  for (int kc = 0; kc < 4; kc++)
    bfr[kc] = *(const half8*)(Bm + n*136 + kc*32 + quad*8);
  floatx4 acc[8];
  #pragma unroll
  for (int mt = 0; mt < 8; mt++){
    floatx4 c = {0.f,0.f,0.f,0.f};
    #pragma unroll
    for (int kc = 0; kc < 4; kc++){
      half8 a = *(const half8*)(A + (mt*16 + n15)*136 + kc*32 + quad*8);
      c = __builtin_amdgcn_mfma_f32_16x16x32_f16(a, bfr[kc], c, 0, 0, 0);
    }
    acc[mt] = c;
  }
  float bias = sb[n];
  __syncthreads();                           // A/Bm reads done -> reuse LDS
  #pragma unroll
  for (int mt = 0; mt < 8; mt++){
    #pragma unroll
    for (int r = 0; r < 4; r++){
      int m = mt*16 + quad*4 + r;
      float v = acc[mt][r] + bias;
      if (act) v = gelu_f(v);
      Ob[m*72 + n] = (f16_t)v;
    }
  }
  __syncthreads();
  f16_t* xo = x + (bh*256 + w0)*64;
  for (int f = tid; f < 1024; f += 256){     // vectorized write-back
    int px = f >> 3, c8 = (f & 7)*8;
    *(float4*)(xo + px*64 + c8) = *(const float4*)((char*)Ob + (px*72 + c8)*2);
  }
  if (dodft){                                // partial w-DFT of this half-row
    int wl0 = wv*32;
    float ar[12], ai[12];
    #pragma unroll
    for (int k = 0; k < 12; k++){ ar[k] = 0.f; ai[k] = 0.f; }
    for (int i = 0; i < 32; i++){
      int wl = wl0 + i;
      float xv = (float)Ob[wl*72 + lane];
      const float4* t = twf4g + (w0 + wl)*6;
      #pragma unroll
      for (int k = 0; k < 6; k++){
        float4 tv = t[k];
        ar[2*k]   += xv*tv.x;  ai[2*k]   += xv*tv.y;
        ar[2*k+1] += xv*tv.z;  ai[2*k+1] += xv*tv.w;
      }
    }
    float2* ps = (wv < 2) ? (ps01 + wv*768) : (ps23 + (wv-2)*768);
    #pragma unroll
    for (int k = 0; k < 12; k++) ps[k*64 + lane] = make_float2(ar[k], ai[k]);
    __syncthreads();
    if (tid < 768){
      float2 a = ps01[tid], b2 = ps01[768 + tid];
      float2 c = ps23[tid], d = ps23[768 + tid];
      float2 s = make_float2(a.x+b2.x+c.x+d.x, a.y+b2.y+c.y+d.y);
      float2* dst = half ? fft1p1 : fft1p0;
      dst[bh*768 + tid] = s;
    }
  }
}

// ------- MFMA conv 3x3 (per-batch weights) + gelu + head, fused; 64-px tiles -
__global__ __launch_bounds__(256) void k_conv_head(const f16_t* __restrict__ x,
      const float* __restrict__ ext, const f16_t* __restrict__ wT,
      const float* __restrict__ tb, const f16_t* __restrict__ f1T,
      const float* __restrict__ f1_b, const f16_t* __restrict__ f2T,
      const float* __restrict__ f2_b, const f16_t* __restrict__ f3T,
      const float* __restrict__ f3_b, float* __restrict__ out){
  __shared__ __align__(16) char sm[37632];
  f16_t* hf   = (f16_t*)sm;                 // [64][72]   9216
  f16_t* z1   = (f16_t*)(sm + 9216);        // [64][136]  17408
  f16_t* z2   = (f16_t*)(sm + 26624);       // [64][72]   9216
  float* tbs  = (float*)(sm + 35840);       // 64
  float* f1bs = (float*)(sm + 36096);       // 128
  float* f2bs = (float*)(sm + 36608);       // 64
  f16_t* f3s  = (f16_t*)(sm + 36864);       // 128 f16
  float* f3bs = (float*)(sm + 37120);       // 2
  f16_t* xt   = (f16_t*)sm;                 // [3][66][72] = 28512 B (conv phase)

  int tid = threadIdx.x;
  int blk = blockIdx.x;
  int wc = blk & 3, h = (blk >> 2) & 127, b = blk >> 9;
  int w0 = wc*64;
  int t_idx = (int)ext[b*6+3] - 5;

  if (tid < 64) tbs[tid] = tb[t_idx*64 + tid];
  else if (tid < 192) f1bs[tid-64] = f1_b[tid-64];
  else f2bs[tid-192] = f2_b[tid-192];
  if (tid < 128) f3s[tid] = f3T[tid];
  if (tid < 2) f3bs[tid] = f3_b[tid];

  for (int f = tid; f < 3168; f += 256){    // xt: 3 rows x 66 px x 64 c
    int c4 = f & 15, r = f >> 4;
    int dy = r/66, pxl = r%66;
    int hh = h - 1 + dy, wg = w0 - 1 + pxl;
    ushort4 v = {0,0,0,0};
    if (hh >= 0 && hh < HH_ && wg >= 0 && wg < WW_)
      v = *(const ushort4*)(x + (((long)b*HH_ + hh)*WW_ + wg)*64 + c4*4);
    *(ushort4*)((unsigned short*)xt + (dy*66 + pxl)*72 + c4*4) = v;
  }
  __syncthreads();

  int lane = tid & 63, wv = tid >> 6;
  int n15 = lane & 15, quad = lane >> 4;

  floatx4 acc[4];
  #pragma unroll
  for (int mt = 0; mt < 4; mt++) acc[mt] = (floatx4){0.f,0.f,0.f,0.f};
  const f16_t* wTt = wT + (long)t_idx*36864;
  for (int tap = 0; tap < 9; tap++){
    int dy = tap/3, dx = tap%3;
    const f16_t* wrow = wTt + (tap*64 + wv*16 + n15)*64;
    #pragma unroll
    for (int kc = 0; kc < 2; kc++){
      half8 bfrag = *(const half8*)(wrow + kc*32 + quad*8);
      #pragma unroll
      for (int mt = 0; mt < 4; mt++){
        int p = mt*16 + n15 + dx;
        half8 a = *(const half8*)(xt + (dy*66 + p)*72 + kc*32 + quad*8);
        acc[mt] = __builtin_amdgcn_mfma_f32_16x16x32_f16(a, bfrag, acc[mt], 0,0,0);
      }
    }
  }
  __syncthreads();                           // xt dead
  {
    int n = wv*16 + n15;
    float bias = tbs[n];
    #pragma unroll
    for (int mt = 0; mt < 4; mt++){
      #pragma unroll
      for (int r = 0; r < 4; r++){
        int m = mt*16 + quad*4 + r;
        hf[m*72 + n] = (f16_t)gelu_f(acc[mt][r] + bias);
      }
    }
  }
  __syncthreads();
  // z1 = gelu(hf . f1^T + f1_b): M=64 N=128 K=64
  #pragma unroll
  for (int nt = 0; nt < 2; nt++){
    int n = wv*32 + nt*16 + n15;
    float bias = f1bs[n];
    half8 bf0 = *(const half8*)(f1T + n*64 + quad*8);
    half8 bf1 = *(const half8*)(f1T + n*64 + 32 + quad*8);
    #pragma unroll
    for (int mt = 0; mt < 4; mt++){
      floatx4 c = {0.f,0.f,0.f,0.f};
      half8 a0 = *(const half8*)(hf + (mt*16 + n15)*72 + quad*8);
      half8 a1 = *(const half8*)(hf + (mt*16 + n15)*72 + 32 + quad*8);
      c = __builtin_amdgcn_mfma_f32_16x16x32_f16(a0, bf0, c, 0,0,0);
      c = __builtin_amdgcn_mfma_f32_16x16x32_f16(a1, bf1, c, 0,0,0);
      #pragma unroll
      for (int r = 0; r < 4; r++){
        int m = mt*16 + quad*4 + r;
        z1[m*136 + n] = (f16_t)gelu_f(c[r] + bias);
      }
    }
  }
  __syncthreads();
  // z2 = gelu(z1 . f2^T + f2_b): M=64 N=64 K=128
  {
    int n = wv*16 + n15;
    float bias = f2bs[n];
    half8 bf[4];
    #pragma unroll
    for (int kc = 0; kc < 4; kc++)
      bf[kc] = *(const half8*)(f2T + n*128 + kc*32 + quad*8);
    #pragma unroll
    for (int mt = 0; mt < 4; mt++){
      floatx4 c = {0.f,0.f,0.f,0.f};
      #pragma unroll
      for (int kc = 0; kc < 4; kc++){
        half8 a = *(const half8*)(z1 + (mt*16 + n15)*136 + kc*32 + quad*8);
        c = __builtin_amdgcn_mfma_f32_16x16x32_f16(a, bf[kc], c, 0,0,0);
      }
      #pragma unroll
      for (int r = 0; r < 4; r++){
        int m = mt*16 + quad*4 + r;
        z2[m*72 + n] = (f16_t)gelu_f(c[r] + bias);
      }
    }
  }
  __syncthreads();
  // f3: out[px][0..1]
  if (tid < 128){
    int px = tid >> 1, oo = tid & 1;
    const f16_t* zr = z2 + px*72;
    const f16_t* fr = f3s + oo*64;
    float a = f3bs[oo];
    #pragma unroll
    for (int g = 0; g < 8; g++){
      half8 zv = *(const half8*)(zr + g*8);
      half8 wv2 = *(const half8*)(fr + g*8);
      #pragma unroll
      for (int q = 0; q < 8; q++) a += (float)zv[q]*(float)wv2[q];
    }
    out[(((long)b*HH_ + h)*WW_ + w0 + px)*2 + oo] = a;
  }
}

extern "C" void kernel_launch(void* const* d_in, const int* in_sizes, int n_in,
                              void* d_out, int out_size, void* d_ws, size_t ws_size,
                              hipStream_t stream){
  const float* inp     = (const float*)d_in[0];
  const float* ext     = (const float*)d_in[1];
  const float* enc_w   = (const float*)d_in[2];
  const float* enc_b   = (const float*)d_in[3];
  const float* w1r     = (const float*)d_in[4];
  const float* w1i     = (const float*)d_in[5];
  const float* w2r     = (const float*)d_in[6];
  const float* w2i     = (const float*)d_in[7];
  const float* ws_w    = (const float*)d_in[8];
  const float* ws_b    = (const float*)d_in[9];
  const float* day_emb = (const float*)d_in[10];
  const float* hour_emb= (const float*)d_in[11];
  const float* e1_w    = (const float*)d_in[12];
  const float* e1_b    = (const float*)d_in[13];
  const float* e2_w    = (const float*)d_in[14];
  const float* e2_b    = (const float*)d_in[15];
  const float* tw      = (const float*)d_in[16];
  const float* tb      = (const float*)d_in[17];
  const float* f1_w    = (const float*)d_in[18];
  const float* f1_b    = (const float*)d_in[19];
  const float* f2_w    = (const float*)d_in[20];
  const float* f2_b    = (const float*)d_in[21];
  const float* f3_w    = (const float*)d_in[22];
  const float* f3_b    = (const float*)d_in[23];
  float* outp = (float*)d_out;

  const size_t need = 257540352;
  if (ws_size < need){
    k_diag<<<dim3(1), dim3(64), 0, stream>>>(outp, (float)(ws_size >> 20));
    return;
  }
  char* p = (char*)d_ws;
  f16_t*  x     = (f16_t*)(p);                   // 134217728 B
  float2* fft1p0= (float2*)(p + 134217728);      // 25165824 B
  float2* fft1p1= (float2*)(p + 159383552);      // 25165824 B
  float2* zi    = (float2*)(p + 184549376);      // 25165824 B
  float2* xft   = (float2*)(p + 209715200);      // 4718592 B
  float*  g     = (float*)(p + 214433792);       // 4194304 B
  float*  g1    = (float*)(p + 218628096);       // 8192 B
  float2* twf   = (float2*)(p + 218636288);      // 24576 B
  float2* thf   = (float2*)(p + 218660864);      // 24576 B
  float2* thi   = (float2*)(p + 218685440);      // 24576 B
  f16_t*  twzh  = (f16_t*)(p + 218710016);       // 16384 B
  f16_t*  wT    = (f16_t*)(p + 218726400);       // 1032192 B
  f16_t*  f1T   = (f16_t*)(p + 219758592);       // 16384 B
  f16_t*  f2T   = (f16_t*)(p + 219774976);       // 16384 B
  f16_t*  f3T   = (f16_t*)(p + 219791360);       // 256 B
  float2* wmix  = (float2*)(p + 219791616);      // 37748736 B

  k_tables<<<dim3(48), dim3(256), 0, stream>>>(twf, thf, thi, twzh);
  k_wprep<<<dim3(2016), dim3(256), 0, stream>>>(tw, wT);
  k_wprep2<<<dim3(65), dim3(256), 0, stream>>>(f1_w, f2_w, f3_w, f1T, f2T, f3T);
  k_mixprep<<<dim3(18432), dim3(256), 0, stream>>>(w1r, w1i, w2r, w2i, wmix);
  k_ext<<<dim3(32), dim3(64), 0, stream>>>(ext, day_emb, hour_emb, e1_w, e1_b, g1);
  k_g<<<dim3(128, 32), dim3(256), 0, stream>>>(g1, e2_w, e2_b, g);
  k_enc<<<dim3(262144), dim3(256), 0, stream>>>(inp, g, enc_w, enc_b, x);
  k_dft_w<<<dim3(1024), dim3(256), 0, stream>>>(x, (const float4*)twf, fft1p0);
  for (int l = 0; l < 4; l++){
    k_dft_h<<<dim3(384), dim3(256), 0, stream>>>(fft1p0, fft1p1, (l > 0) ? 1 : 0,
                                                 thf, xft);
    k_mix<<<dim3(576), dim3(256), 0, stream>>>(wmix, l, xft);
    k_ifft_h<<<dim3(384), dim3(256), 0, stream>>>(xft, thi, zi);
    k_iw_mfma<<<dim3(8192), dim3(256), 0, stream>>>(x, zi, ws_w, ws_b, twzh,
                       (const float4*)twf, fft1p0, fft1p1,
                       l, (l < 3) ? 1 : 0, (l < 3) ? 1 : 0);
  }
  k_conv_head<<<dim3(16384), dim3(256), 0, stream>>>(x, ext, wT, tb,
                     f1T, f1_b, f2T, f2_b, f3T, f3_b, outp);
}

// Round 7
// 1654.045 us; speedup vs baseline: 1.2083x; 1.2083x over previous
//
#include <hip/hip_runtime.h>
#include <math.h>

#define BB 32
#define HH_ 128
#define WW_ 256

typedef _Float16 f16_t;
typedef _Float16 half8 __attribute__((ext_vector_type(8)));
typedef float floatx4 __attribute__((ext_vector_type(4)));

__device__ __forceinline__ float gelu_f(float v){
  return 0.5f * v * (1.0f + erff(v * 0.70710678118654752f));
}

__global__ void k_diag(float* out, float v){ out[threadIdx.x] = v; }

// ---------------- twiddle tables -------------------------------------------
__global__ void k_tables(float2* twf, float2* thf, float2* thi, f16_t* twzh){
  int t = blockIdx.x*256 + threadIdx.x;
  const double PI2 = 6.283185307179586476925286766559;
  if (t < 3072){                       // forward w-DFT: [w][ky]
    int w = t/12, ky = t%12;
    double a = -PI2 * (double)(w*ky) / 256.0;
    twf[t] = make_float2((float)cos(a), (float)sin(a));
  } else if (t < 6144){                // forward h-DFT: [h][j], kx {0..11,116..127}
    int f = t-3072; int h = f/24, j = f%24;
    int kx = (j<12)? j : j+104;
    double a = -PI2 * (double)(h*kx) / 128.0;
    thf[f] = make_float2((float)cos(a), (float)sin(a));
  } else if (t < 9216){                // inverse h (includes 1/128)
    int f = t-6144; int h = f/24, j = f%24;
    int kx = (j<12)? j : j+104;
    double a = PI2 * (double)(h*kx) / 128.0;
    thi[f] = make_float2((float)(cos(a)/128.0), (float)(sin(a)/128.0));
  } else if (t < 12288){               // inverse w (c2r) coefs, f16, [w][32]
    int f = t-9216; int w = f/12, ky = f%12;
    double a = PI2 * (double)(w*ky) / 256.0;
    double s = (ky==0)? 1.0 : 2.0;
    twzh[w*32 + ky]      = (f16_t)( s*cos(a)/256.0);
    twzh[w*32 + 12 + ky] = (f16_t)(-s*sin(a)/256.0);
    if (ky < 8) twzh[w*32 + 24 + ky] = (f16_t)0.f;
  }
}

// ---------------- conv weight transpose: wT[t][tap][o][c] f16 ----------------
__global__ __launch_bounds__(256) void k_wprep(const float* __restrict__ tw,
                                               f16_t* __restrict__ wT){
  int t = blockIdx.x*256 + threadIdx.x;     // < 14*9*64*64 = 516096
  int c = t & 63, o = (t >> 6) & 63, r = t >> 12;
  int tap = r % 9, tt = r / 9;
  wT[t] = (f16_t)tw[(((tt*64 + o)*64 + c)*9) + tap];
}

// ---------------- head weights -> f16 ---------------------------------------
__global__ __launch_bounds__(256) void k_wprep2(const float* __restrict__ f1_w,
      const float* __restrict__ f2_w, const float* __restrict__ f3_w,
      f16_t* __restrict__ f1T, f16_t* __restrict__ f2T, f16_t* __restrict__ f3T){
  int t = blockIdx.x*256 + threadIdx.x;
  if (t < 8192) f1T[t] = (f16_t)f1_w[t];
  else if (t < 16384) f2T[t-8192] = (f16_t)f2_w[t-8192];
  else if (t < 16512) f3T[t-16384] = (f16_t)f3_w[t-16384];
}

// -------- spectral weight transpose: wmix[l][j][ky][i*64+o] float2 ----------
__global__ __launch_bounds__(256) void k_mixprep(const float* __restrict__ w1r,
      const float* __restrict__ w1i, const float* __restrict__ w2r,
      const float* __restrict__ w2i, float2* __restrict__ wmix){
  long t = (long)blockIdx.x*256 + threadIdx.x;   // < 4*24*12*4096
  int io = (int)(t & 4095);
  int r  = (int)(t >> 12);
  int ky = r % 12; int r2 = r / 12;
  int j  = r2 % 24; int l = r2 / 24;
  int i = io >> 6, o = io & 63;
  const float* wr; const float* wi; int kx;
  if (j < 12){ wr = w1r; wi = w1i; kx = j; } else { wr = w2r; wi = w2i; kx = j - 12; }
  long src = (((long)l*64 + i)*64 + o)*144 + kx*12 + ky;
  wmix[t] = make_float2(wr[src], wi[src]);
}

// ---------------- ext -> g1 (B x 64) ----------------------------------------
__global__ void k_ext(const float* __restrict__ ext, const float* __restrict__ day_emb,
                      const float* __restrict__ hour_emb, const float* __restrict__ e1_w,
                      const float* __restrict__ e1_b, float* __restrict__ g1){
  int b = blockIdx.x, j = threadIdx.x;
  const float* e = ext + b*6;
  float emb[6];
  emb[0] = e[0];
  int d  = (int)e[2];
  emb[1] = day_emb[d*2];  emb[2] = day_emb[d*2+1];
  int hr = (int)e[3];
  emb[3] = hour_emb[hr*3]; emb[4] = hour_emb[hr*3+1]; emb[5] = hour_emb[hr*3+2];
  float acc = e1_b[j];
  #pragma unroll
  for (int k = 0; k < 6; k++) acc += emb[k]*e1_w[j*6+k];
  g1[b*64 + j] = gelu_f(acc);
}

// ---------------- g1 -> g (B x HW) ------------------------------------------
__global__ __launch_bounds__(256) void k_g(const float* __restrict__ g1,
      const float* __restrict__ e2_w, const float* __restrict__ e2_b, float* __restrict__ g){
  int b = blockIdx.y;
  int hw = blockIdx.x*256 + threadIdx.x;
  __shared__ float s[64];
  if (threadIdx.x < 64) s[threadIdx.x] = g1[b*64 + threadIdx.x];
  __syncthreads();
  const float4* wrow = (const float4*)(e2_w + (long)hw*64);
  float acc = e2_b[hw];
  #pragma unroll
  for (int k = 0; k < 16; k++){
    float4 v = wrow[k];
    acc += v.x*s[4*k] + v.y*s[4*k+1] + v.z*s[4*k+2] + v.w*s[4*k+3];
  }
  g[(long)b*(HH_*WW_) + hw] = gelu_f(acc);
}

// ---------------- encoder: x[b,h,w,c] f16 -----------------------------------
__global__ __launch_bounds__(256) void k_enc(const float* __restrict__ inp,
      const float* __restrict__ g, const float* __restrict__ enc_w,
      const float* __restrict__ enc_b, f16_t* __restrict__ x){
  long t = (long)blockIdx.x*256 + threadIdx.x;   // < B*HW*64
  int c = (int)(t & 63);
  long pix = t >> 6;
  const float* ip = inp + pix*4;
  const float* wr = enc_w + c*5;
  float acc = enc_b[c] + ip[0]*wr[0] + ip[1]*wr[1] + ip[2]*wr[2] + ip[3]*wr[3] + g[pix]*wr[4];
  x[t] = (f16_t)acc;
}

// ---------------- forward DFT along w: fft1[b,h,ky,c] -----------------------
__global__ __launch_bounds__(256) void k_dft_w(const f16_t* __restrict__ x,
      const float4* __restrict__ twf4, float2* __restrict__ fft1){
  __shared__ float4 tw[1536];                      // [w][6]
  for (int f = threadIdx.x; f < 1536; f += 256) tw[f] = twf4[f];
  __syncthreads();
  int wave = threadIdx.x >> 6, lane = threadIdx.x & 63;
  long row = (long)blockIdx.x*4 + wave;            // b*H + h
  const f16_t* xr = x + row*16384 + lane;
  float ar[12], ai[12];
  #pragma unroll
  for (int k = 0; k < 12; k++){ ar[k] = 0.f; ai[k] = 0.f; }
  for (int w = 0; w < 256; w++){
    float xv = (float)xr[(long)w*64];
    const float4* t = &tw[w*6];
    #pragma unroll
    for (int k = 0; k < 6; k++){
      float4 tv = t[k];
      ar[2*k]   += xv*tv.x;  ai[2*k]   += xv*tv.y;
      ar[2*k+1] += xv*tv.z;  ai[2*k+1] += xv*tv.w;
    }
  }
  float2* op = fft1 + row*768 + lane;
  #pragma unroll
  for (int ky = 0; ky < 12; ky++) op[ky*64] = make_float2(ar[ky], ai[ky]);
}

// ------- forward DFT along h, tiled: block=(b,ky,jhalf), 768 blocks ---------
__global__ __launch_bounds__(256) void k_dft_h(const float2* __restrict__ fft1,
      const float2* __restrict__ thf, float2* __restrict__ xft){
  __shared__ float2 th[3072];                      // [h][24]
  __shared__ float2 xch[2048];                     // [32 h][64 c]
  int tid = threadIdx.x;
  for (int f = tid; f < 3072; f += 256) th[f] = thf[f];
  int blk = blockIdx.x;                            // < 768
  int b = blk / 24, r = blk % 24;
  int ky = r % 12, jh = r / 12;                    // j half: [jh*12, jh*12+12)
  int wv = tid >> 6, lane = tid & 63;
  float2 acc[3];
  #pragma unroll
  for (int q = 0; q < 3; q++) acc[q] = make_float2(0.f, 0.f);
  long base = (long)b*98304 + ky*64;
  for (int ch = 0; ch < 4; ch++){
    __syncthreads();
    for (int f = tid; f < 2048; f += 256){
      int hh = f >> 6, c = f & 63;
      xch[f] = fft1[base + (long)(ch*32 + hh)*768 + c];
    }
    __syncthreads();
    for (int hh = 0; hh < 32; hh++){
      float2 v = xch[hh*64 + lane];
      int hg = ch*32 + hh;
      #pragma unroll
      for (int q = 0; q < 3; q++){
        float2 t = th[hg*24 + jh*12 + q*4 + wv];
        acc[q].x += t.x*v.x - t.y*v.y;
        acc[q].y += t.x*v.y + t.y*v.x;
      }
    }
  }
  #pragma unroll
  for (int q = 0; q < 3; q++){
    int j = jh*12 + q*4 + wv;
    xft[((long)b*288 + j*12 + ky)*64 + lane] = acc[q];
  }
}

// -------- mode mixing IN PLACE (coalesced weights), 576 blocks --------------
__global__ __launch_bounds__(256) void k_mix(const float2* __restrict__ wmix,
      int layer, float2* __restrict__ xft){
  __shared__ float2 wl[4096];                      // [i][o]
  int jk = blockIdx.x >> 1;
  int bh2 = blockIdx.x & 1;
  int j = jk / 12, ky = jk % 12;
  const float2* wsrc = wmix + ((long)layer*288 + jk)*4096;
  for (int f = threadIdx.x; f < 4096; f += 256) wl[f] = wsrc[f];
  __syncthreads();
  int wave = threadIdx.x >> 6, lane = threadIdx.x & 63;
  for (int b = bh2*16 + wave; b < bh2*16 + 16; b += 4){
    long base = ((long)b*288 + j*12 + ky)*64;
    float2 mine = xft[base + lane];
    float re = 0.f, im = 0.f;
    #pragma unroll 8
    for (int i = 0; i < 64; i++){
      float vr = __shfl(mine.x, i);
      float vi = __shfl(mine.y, i);
      float2 ww = wl[i*64 + lane];
      re += vr*ww.x - vi*ww.y;
      im += vr*ww.y + vi*ww.x;
    }
    xft[base + lane] = make_float2(re, im);
  }
}

// ------- inverse DFT along h, tiled: block=(b,ky,hhalf), 768 blocks ---------
__global__ __launch_bounds__(256) void k_ifft_h(const float2* __restrict__ c3,
      const float2* __restrict__ thi, float2* __restrict__ zi){
  __shared__ float2 th[3072];                      // [h][24]
  int tid = threadIdx.x;
  for (int f = tid; f < 3072; f += 256) th[f] = thi[f];
  int blk = blockIdx.x;                            // < 768
  int b = blk / 24, r = blk % 24;
  int ky = r % 12, hh2 = r / 12;                   // h half: [hh2*64, hh2*64+64)
  int wv = tid >> 6, lane = tid & 63;
  float2 cr[24];
  const float2* src = c3 + (long)b*18432 + ky*64 + lane;
  #pragma unroll
  for (int j = 0; j < 24; j++) cr[j] = src[(long)j*768];
  __syncthreads();
  for (int q = 0; q < 16; q++){
    int h = hh2*64 + q*4 + wv;
    float re = 0.f, im = 0.f;
    #pragma unroll
    for (int j = 0; j < 24; j++){
      float2 t = th[h*24 + j];
      re += t.x*cr[j].x - t.y*cr[j].y;
      im += t.x*cr[j].y + t.y*cr[j].x;
    }
    zi[((long)b*128 + h)*768 + ky*64 + lane] = make_float2(re, im);
  }
}

// ------- MFMA: inverse-w + channel skip + bias + (gelu), in place on x ------
__global__ __launch_bounds__(256) void k_iw_mfma(f16_t* __restrict__ x,
      const float2* __restrict__ zi, const float* __restrict__ ws_w,
      const float* __restrict__ ws_b, const f16_t* __restrict__ twzh,
      int layer, int act){
  __shared__ __align__(16) char sm[52736];
  f16_t* A  = (f16_t*)sm;                   // [128][136]; reused as Ob [128][72]
  f16_t* Bm = (f16_t*)(sm + 34816);         // [64][136]
  float* sb = (float*)(sm + 52224);         // [64]
  f16_t* Ob = (f16_t*)sm;
  int tid = threadIdx.x;
  int blk = blockIdx.x;
  int half = blk & 1;
  long bh = blk >> 1;                       // b*128 + h
  int w0 = half*128;
  const f16_t* xrow = x + (bh*256 + w0)*64;
  for (int f = tid; f < 1024; f += 256){    // x part, 16B copies
    int px = f >> 3, c8 = (f & 7)*8;
    *(float4*)((char*)A + (px*136 + c8)*2) = *(const float4*)(xrow + px*64 + c8);
  }
  for (int f = tid; f < 3072; f += 256){    // twz part (duplicated hi/lo)
    int px = f/24, k = f%24;
    f16_t v = twzh[(w0+px)*32 + k];
    A[px*136 + 64 + k] = v;
    A[px*136 + 88 + k] = v;
  }
  for (int f = tid; f < 3072; f += 256){    // A zero pad k=112..135
    int px = f/24, k = f%24;
    A[px*136 + 112 + k] = (f16_t)0.f;
  }
  const float* wsl = ws_w + (long)layer*4096;
  for (int f = tid; f < 1024; f += 256){    // B ws part
    int o = f >> 4, c4 = f & 15;
    float4 v = *(const float4*)(wsl + o*64 + c4*4);
    f16_t* d = Bm + o*136 + c4*4;
    d[0]=(f16_t)v.x; d[1]=(f16_t)v.y; d[2]=(f16_t)v.z; d[3]=(f16_t)v.w;
  }
  const float2* zrow = zi + bh*768;
  for (int f = tid; f < 768; f += 256){     // B z hi/lo
    int o = f & 63, ky = f >> 6;
    float2 v = zrow[ky*64 + o];
    f16_t hr = (f16_t)v.x; f16_t hi_ = (f16_t)v.y;
    Bm[o*136 + 64 + ky] = hr;
    Bm[o*136 + 76 + ky] = hi_;
    Bm[o*136 + 88 + ky] = (f16_t)(v.x - (float)hr);
    Bm[o*136 +100 + ky] = (f16_t)(v.y - (float)hi_);
  }
  for (int f = tid; f < 1536; f += 256){    // B zero pad
    int o = f/24, k = f%24;
    Bm[o*136 + 112 + k] = (f16_t)0.f;
  }
  if (tid < 64) sb[tid] = ws_b[layer*64 + tid];
  __syncthreads();
  int lane = tid & 63, wv = tid >> 6;
  int n15 = lane & 15, quad = lane >> 4;
  int n = wv*16 + n15;
  half8 bfr[4];
  #pragma unroll
  for (int kc = 0; kc < 4; kc++)
    bfr[kc] = *(const half8*)(Bm + n*136 + kc*32 + quad*8);
  floatx4 acc[8];
  #pragma unroll
  for (int mt = 0; mt < 8; mt++){
    floatx4 c = {0.f,0.f,0.f,0.f};
    #pragma unroll
    for (int kc = 0; kc < 4; kc++){
      half8 a = *(const half8*)(A + (mt*16 + n15)*136 + kc*32 + quad*8);
      c = __builtin_amdgcn_mfma_f32_16x16x32_f16(a, bfr[kc], c, 0, 0, 0);
    }
    acc[mt] = c;
  }
  float bias = sb[n];
  __syncthreads();                           // A reads done -> reuse as Ob
  #pragma unroll
  for (int mt = 0; mt < 8; mt++){
    #pragma unroll
    for (int r = 0; r < 4; r++){
      int m = mt*16 + quad*4 + r;
      float v = acc[mt][r] + bias;
      if (act) v = gelu_f(v);
      Ob[m*72 + n] = (f16_t)v;
    }
  }
  __syncthreads();
  f16_t* xo = x + (bh*256 + w0)*64;
  for (int f = tid; f < 1024; f += 256){     // vectorized write-back
    int px = f >> 3, c8 = (f & 7)*8;
    *(float4*)(xo + px*64 + c8) = *(const float4*)((char*)Ob + (px*72 + c8)*2);
  }
}

// ------- MFMA conv 3x3 (per-batch weights) + gelu + head, fused; 64-px tiles -
__global__ __launch_bounds__(256) void k_conv_head(const f16_t* __restrict__ x,
      const float* __restrict__ ext, const f16_t* __restrict__ wT,
      const float* __restrict__ tb, const f16_t* __restrict__ f1T,
      const float* __restrict__ f1_b, const f16_t* __restrict__ f2T,
      const float* __restrict__ f2_b, const f16_t* __restrict__ f3T,
      const float* __restrict__ f3_b, float* __restrict__ out){
  __shared__ __align__(16) char sm[37632];
  f16_t* hf   = (f16_t*)sm;                 // [64][72]   9216
  f16_t* z1   = (f16_t*)(sm + 9216);        // [64][136]  17408
  f16_t* z2   = (f16_t*)(sm + 26624);       // [64][72]   9216
  float* tbs  = (float*)(sm + 35840);       // 64
  float* f1bs = (float*)(sm + 36096);       // 128
  float* f2bs = (float*)(sm + 36608);       // 64
  f16_t* f3s  = (f16_t*)(sm + 36864);       // 128 f16
  float* f3bs = (float*)(sm + 37120);       // 2
  f16_t* xt   = (f16_t*)sm;                 // [3][66][72] = 28512 B (conv phase)

  int tid = threadIdx.x;
  int blk = blockIdx.x;
  int wc = blk & 3, h = (blk >> 2) & 127, b = blk >> 9;
  int w0 = wc*64;
  int t_idx = (int)ext[b*6+3] - 5;

  if (tid < 64) tbs[tid] = tb[t_idx*64 + tid];
  else if (tid < 192) f1bs[tid-64] = f1_b[tid-64];
  else f2bs[tid-192] = f2_b[tid-192];
  if (tid < 128) f3s[tid] = f3T[tid];
  if (tid < 2) f3bs[tid] = f3_b[tid];

  for (int f = tid; f < 3168; f += 256){    // xt: 3 rows x 66 px x 64 c
    int c4 = f & 15, r = f >> 4;
    int dy = r/66, pxl = r%66;
    int hh = h - 1 + dy, wg = w0 - 1 + pxl;
    ushort4 v = {0,0,0,0};
    if (hh >= 0 && hh < HH_ && wg >= 0 && wg < WW_)
      v = *(const ushort4*)(x + (((long)b*HH_ + hh)*WW_ + wg)*64 + c4*4);
    *(ushort4*)((unsigned short*)xt + (dy*66 + pxl)*72 + c4*4) = v;
  }
  __syncthreads();

  int lane = tid & 63, wv = tid >> 6;
  int n15 = lane & 15, quad = lane >> 4;

  floatx4 acc[4];
  #pragma unroll
  for (int mt = 0; mt < 4; mt++) acc[mt] = (floatx4){0.f,0.f,0.f,0.f};
  const f16_t* wTt = wT + (long)t_idx*36864;
  for (int tap = 0; tap < 9; tap++){
    int dy = tap/3, dx = tap%3;
    const f16_t* wrow = wTt + (tap*64 + wv*16 + n15)*64;
    #pragma unroll
    for (int kc = 0; kc < 2; kc++){
      half8 bfrag = *(const half8*)(wrow + kc*32 + quad*8);
      #pragma unroll
      for (int mt = 0; mt < 4; mt++){
        int p = mt*16 + n15 + dx;
        half8 a = *(const half8*)(xt + (dy*66 + p)*72 + kc*32 + quad*8);
        acc[mt] = __builtin_amdgcn_mfma_f32_16x16x32_f16(a, bfrag, acc[mt], 0,0,0);
      }
    }
  }
  __syncthreads();                           // xt dead
  {
    int n = wv*16 + n15;
    float bias = tbs[n];
    #pragma unroll
    for (int mt = 0; mt < 4; mt++){
      #pragma unroll
      for (int r = 0; r < 4; r++){
        int m = mt*16 + quad*4 + r;
        hf[m*72 + n] = (f16_t)gelu_f(acc[mt][r] + bias);
      }
    }
  }
  __syncthreads();
  // z1 = gelu(hf . f1^T + f1_b): M=64 N=128 K=64
  #pragma unroll
  for (int nt = 0; nt < 2; nt++){
    int n = wv*32 + nt*16 + n15;
    float bias = f1bs[n];
    half8 bf0 = *(const half8*)(f1T + n*64 + quad*8);
    half8 bf1 = *(const half8*)(f1T + n*64 + 32 + quad*8);
    #pragma unroll
    for (int mt = 0; mt < 4; mt++){
      floatx4 c = {0.f,0.f,0.f,0.f};
      half8 a0 = *(const half8*)(hf + (mt*16 + n15)*72 + quad*8);
      half8 a1 = *(const half8*)(hf + (mt*16 + n15)*72 + 32 + quad*8);
      c = __builtin_amdgcn_mfma_f32_16x16x32_f16(a0, bf0, c, 0,0,0);
      c = __builtin_amdgcn_mfma_f32_16x16x32_f16(a1, bf1, c, 0,0,0);
      #pragma unroll
      for (int r = 0; r < 4; r++){
        int m = mt*16 + quad*4 + r;
        z1[m*136 + n] = (f16_t)gelu_f(c[r] + bias);
      }
    }
  }
  __syncthreads();
  // z2 = gelu(z1 . f2^T + f2_b): M=64 N=64 K=128
  {
    int n = wv*16 + n15;
    float bias = f2bs[n];
    half8 bf[4];
    #pragma unroll
    for (int kc = 0; kc < 4; kc++)
      bf[kc] = *(const half8*)(f2T + n*128 + kc*32 + quad*8);
    #pragma unroll
    for (int mt = 0; mt < 4; mt++){
      floatx4 c = {0.f,0.f,0.f,0.f};
      #pragma unroll
      for (int kc = 0; kc < 4; kc++){
        half8 a = *(const half8*)(z1 + (mt*16 + n15)*136 + kc*32 + quad*8);
        c = __builtin_amdgcn_mfma_f32_16x16x32_f16(a, bf[kc], c, 0,0,0);
      }
      #pragma unroll
      for (int r = 0; r < 4; r++){
        int m = mt*16 + quad*4 + r;
        z2[m*72 + n] = (f16_t)gelu_f(c[r] + bias);
      }
    }
  }
  __syncthreads();
  // f3: out[px][0..1]
  if (tid < 128){
    int px = tid >> 1, oo = tid & 1;
    const f16_t* zr = z2 + px*72;
    const f16_t* fr = f3s + oo*64;
    float a = f3bs[oo];
    #pragma unroll
    for (int g = 0; g < 8; g++){
      half8 zv = *(const half8*)(zr + g*8);
      half8 wv2 = *(const half8*)(fr + g*8);
      #pragma unroll
      for (int q = 0; q < 8; q++) a += (float)zv[q]*(float)wv2[q];
    }
    out[(((long)b*HH_ + h)*WW_ + w0 + px)*2 + oo] = a;
  }
}

extern "C" void kernel_launch(void* const* d_in, const int* in_sizes, int n_in,
                              void* d_out, int out_size, void* d_ws, size_t ws_size,
                              hipStream_t stream){
  const float* inp     = (const float*)d_in[0];
  const float* ext     = (const float*)d_in[1];
  const float* enc_w   = (const float*)d_in[2];
  const float* enc_b   = (const float*)d_in[3];
  const float* w1r     = (const float*)d_in[4];
  const float* w1i     = (const float*)d_in[5];
  const float* w2r     = (const float*)d_in[6];
  const float* w2i     = (const float*)d_in[7];
  const float* ws_w    = (const float*)d_in[8];
  const float* ws_b    = (const float*)d_in[9];
  const float* day_emb = (const float*)d_in[10];
  const float* hour_emb= (const float*)d_in[11];
  const float* e1_w    = (const float*)d_in[12];
  const float* e1_b    = (const float*)d_in[13];
  const float* e2_w    = (const float*)d_in[14];
  const float* e2_b    = (const float*)d_in[15];
  const float* tw      = (const float*)d_in[16];
  const float* tb      = (const float*)d_in[17];
  const float* f1_w    = (const float*)d_in[18];
  const float* f1_b    = (const float*)d_in[19];
  const float* f2_w    = (const float*)d_in[20];
  const float* f2_b    = (const float*)d_in[21];
  const float* f3_w    = (const float*)d_in[22];
  const float* f3_b    = (const float*)d_in[23];
  float* outp = (float*)d_out;

  const size_t need = 207208704;
  if (ws_size < need){
    k_diag<<<dim3(1), dim3(64), 0, stream>>>(outp, (float)(ws_size >> 20));
    return;
  }
  char* p = (char*)d_ws;
  f16_t*  x    = (f16_t*)(p);                    // 134217728 B
  float2* fft1 = (float2*)(p + 134217728);       // 25165824 B (zi alias)
  float2* xft  = (float2*)(p + 159383552);       // 4718592 B
  float*  g    = (float*)(p + 164102144);        // 4194304 B
  float*  g1   = (float*)(p + 168296448);        // 8192 B
  float2* twf  = (float2*)(p + 168304640);       // 24576 B
  float2* thf  = (float2*)(p + 168329216);       // 24576 B
  float2* thi  = (float2*)(p + 168353792);       // 24576 B
  f16_t*  twzh = (f16_t*)(p + 168378368);        // 16384 B
  f16_t*  wT   = (f16_t*)(p + 168394752);        // 1032192 B
  f16_t*  f1T  = (f16_t*)(p + 169426944);        // 16384 B
  f16_t*  f2T  = (f16_t*)(p + 169443328);        // 16384 B
  f16_t*  f3T  = (f16_t*)(p + 169459712);        // 256 B
  float2* wmix = (float2*)(p + 169459968);       // 37748736 B
  float2* zi   = fft1;

  k_tables<<<dim3(48), dim3(256), 0, stream>>>(twf, thf, thi, twzh);
  k_wprep<<<dim3(2016), dim3(256), 0, stream>>>(tw, wT);
  k_wprep2<<<dim3(65), dim3(256), 0, stream>>>(f1_w, f2_w, f3_w, f1T, f2T, f3T);
  k_mixprep<<<dim3(18432), dim3(256), 0, stream>>>(w1r, w1i, w2r, w2i, wmix);
  k_ext<<<dim3(32), dim3(64), 0, stream>>>(ext, day_emb, hour_emb, e1_w, e1_b, g1);
  k_g<<<dim3(128, 32), dim3(256), 0, stream>>>(g1, e2_w, e2_b, g);
  k_enc<<<dim3(262144), dim3(256), 0, stream>>>(inp, g, enc_w, enc_b, x);
  for (int l = 0; l < 4; l++){
    k_dft_w<<<dim3(1024), dim3(256), 0, stream>>>(x, (const float4*)twf, fft1);
    k_dft_h<<<dim3(768), dim3(256), 0, stream>>>(fft1, thf, xft);
    k_mix<<<dim3(576), dim3(256), 0, stream>>>(wmix, l, xft);
    k_ifft_h<<<dim3(768), dim3(256), 0, stream>>>(xft, thi, zi);
    k_iw_mfma<<<dim3(8192), dim3(256), 0, stream>>>(x, zi, ws_w, ws_b, twzh,
                                                    l, (l < 3) ? 1 : 0);
  }
  k_conv_head<<<dim3(16384), dim3(256), 0, stream>>>(x, ext, wT, tb,
                     f1T, f1_b, f2T, f2_b, f3T, f3_b, outp);
}

// Round 8
// 1607.836 us; speedup vs baseline: 1.2431x; 1.0287x over previous
//
#include <hip/hip_runtime.h>
#include <math.h>

#define BB 32
#define HH_ 128
#define WW_ 256

typedef _Float16 f16_t;
typedef _Float16 half8 __attribute__((ext_vector_type(8)));
typedef float floatx4 __attribute__((ext_vector_type(4)));

__device__ __forceinline__ float gelu_f(float v){
  return 0.5f * v * (1.0f + erff(v * 0.70710678118654752f));
}

__global__ void k_diag(float* out, float v){ out[threadIdx.x] = v; }

// ---------------- twiddle tables -------------------------------------------
__global__ void k_tables(float2* twf, float2* thf, float2* thi, f16_t* twzh){
  int t = blockIdx.x*256 + threadIdx.x;
  const double PI2 = 6.283185307179586476925286766559;
  if (t < 3072){                       // forward w-DFT: [w][ky]
    int w = t/12, ky = t%12;
    double a = -PI2 * (double)(w*ky) / 256.0;
    twf[t] = make_float2((float)cos(a), (float)sin(a));
  } else if (t < 6144){                // forward h-DFT: [h][j], kx {0..11,116..127}
    int f = t-3072; int h = f/24, j = f%24;
    int kx = (j<12)? j : j+104;
    double a = -PI2 * (double)(h*kx) / 128.0;
    thf[f] = make_float2((float)cos(a), (float)sin(a));
  } else if (t < 9216){                // inverse h (includes 1/128)
    int f = t-6144; int h = f/24, j = f%24;
    int kx = (j<12)? j : j+104;
    double a = PI2 * (double)(h*kx) / 128.0;
    thi[f] = make_float2((float)(cos(a)/128.0), (float)(sin(a)/128.0));
  } else if (t < 12288){               // inverse w (c2r) coefs, f16, [w][32]
    int f = t-9216; int w = f/12, ky = f%12;
    double a = PI2 * (double)(w*ky) / 256.0;
    double s = (ky==0)? 1.0 : 2.0;
    twzh[w*32 + ky]      = (f16_t)( s*cos(a)/256.0);
    twzh[w*32 + 12 + ky] = (f16_t)(-s*sin(a)/256.0);
    if (ky < 8) twzh[w*32 + 24 + ky] = (f16_t)0.f;
  }
}

// ------- conv weight transpose via LDS (coalesced both sides) ---------------
// wT[tt][tap][o][c] f16  <-  tw[tt][o][c][tap] f32
__global__ __launch_bounds__(256) void k_wprep(const float* __restrict__ tw,
                                               f16_t* __restrict__ wT){
  __shared__ float s[9216];                 // [o16][c][tap] for one (tt, og)
  int blk = blockIdx.x;                     // 56 = 14 tt x 4 og
  int og = blk & 3, tt = blk >> 2;
  int tid = threadIdx.x;
  const float* src = tw + (long)tt*36864 + og*9216;
  for (int f = tid; f < 9216; f += 256) s[f] = src[f];     // fully coalesced
  __syncthreads();
  for (int f = tid; f < 9216; f += 256){
    int c = f & 63; int r = f >> 6;
    int o16 = r % 16, tap = r / 16;
    float v = s[(o16*64 + c)*9 + tap];      // stride 9 (coprime 32): no conflicts
    wT[(((long)tt*9 + tap)*64 + og*16 + o16)*64 + c] = (f16_t)v;  // coalesced
  }
}

// ---------------- head weights -> f16 ---------------------------------------
__global__ __launch_bounds__(256) void k_wprep2(const float* __restrict__ f1_w,
      const float* __restrict__ f2_w, const float* __restrict__ f3_w,
      f16_t* __restrict__ f1T, f16_t* __restrict__ f2T, f16_t* __restrict__ f3T){
  int t = blockIdx.x*256 + threadIdx.x;
  if (t < 8192) f1T[t] = (f16_t)f1_w[t];
  else if (t < 16384) f2T[t-8192] = (f16_t)f2_w[t-8192];
  else if (t < 16512) f3T[t-16384] = (f16_t)f3_w[t-16384];
}

// ------- spectral weight transpose via LDS (coalesced both sides) -----------
// wmix[l][j][ky][i*64+o] float2  <-  w{1,2}{r,i}[l][i][o][kx][ky]
__global__ __launch_bounds__(256) void k_mixprep(const float* __restrict__ w1r,
      const float* __restrict__ w1i, const float* __restrict__ w2r,
      const float* __restrict__ w2i, float2* __restrict__ wmix){
  __shared__ float sr[6656], si[6656];      // [i8][o][ky] padded to 13
  int blk = blockIdx.x;                     // 768 = l(4) x sel(2) x kx(12) x ig(8)
  int ig  = blk & 7;
  int kx  = (blk >> 3) % 12;
  int sel = (blk / 96) & 1;
  int l   = blk / 192;
  const float* wr = sel ? w2r : w1r;
  const float* wi = sel ? w2i : w1i;
  int tid = threadIdx.x;
  for (int f = tid; f < 6144; f += 256){
    int i8 = f / 768; int rem = f % 768;
    int o = rem / 12, ky = rem % 12;
    long addr = (((long)l*64 + ig*8 + i8)*64 + o)*144 + kx*12 + ky; // 48B segments
    sr[(i8*64 + o)*13 + ky] = wr[addr];
    si[(i8*64 + o)*13 + ky] = wi[addr];
  }
  __syncthreads();
  int j = sel ? (kx + 12) : kx;
  for (int f = tid; f < 6144; f += 256){
    int o = f & 63; int r = f >> 6;
    int ky = r % 12, i8 = r / 12;
    int sidx = (i8*64 + o)*13 + ky;         // stride 13: conflict-free
    wmix[(((long)l*288 + j*12 + ky))*4096 + (ig*8 + i8)*64 + o] =
        make_float2(sr[sidx], si[sidx]);    // lanes o-consecutive: coalesced
  }
}

// ---------------- ext -> g1 (B x 64) ----------------------------------------
__global__ void k_ext(const float* __restrict__ ext, const float* __restrict__ day_emb,
                      const float* __restrict__ hour_emb, const float* __restrict__ e1_w,
                      const float* __restrict__ e1_b, float* __restrict__ g1){
  int b = blockIdx.x, j = threadIdx.x;
  const float* e = ext + b*6;
  float emb[6];
  emb[0] = e[0];
  int d  = (int)e[2];
  emb[1] = day_emb[d*2];  emb[2] = day_emb[d*2+1];
  int hr = (int)e[3];
  emb[3] = hour_emb[hr*3]; emb[4] = hour_emb[hr*3+1]; emb[5] = hour_emb[hr*3+2];
  float acc = e1_b[j];
  #pragma unroll
  for (int k = 0; k < 6; k++) acc += emb[k]*e1_w[j*6+k];
  g1[b*64 + j] = gelu_f(acc);
}

// ---------------- g1 -> g (B x HW) ------------------------------------------
__global__ __launch_bounds__(256) void k_g(const float* __restrict__ g1,
      const float* __restrict__ e2_w, const float* __restrict__ e2_b, float* __restrict__ g){
  int b = blockIdx.y;
  int hw = blockIdx.x*256 + threadIdx.x;
  __shared__ float s[64];
  if (threadIdx.x < 64) s[threadIdx.x] = g1[b*64 + threadIdx.x];
  __syncthreads();
  const float4* wrow = (const float4*)(e2_w + (long)hw*64);
  float acc = e2_b[hw];
  #pragma unroll
  for (int k = 0; k < 16; k++){
    float4 v = wrow[k];
    acc += v.x*s[4*k] + v.y*s[4*k+1] + v.z*s[4*k+2] + v.w*s[4*k+3];
  }
  g[(long)b*(HH_*WW_) + hw] = gelu_f(acc);
}

// ---------------- encoder: x[b,h,w,c] f16 -----------------------------------
__global__ __launch_bounds__(256) void k_enc(const float* __restrict__ inp,
      const float* __restrict__ g, const float* __restrict__ enc_w,
      const float* __restrict__ enc_b, f16_t* __restrict__ x){
  long t = (long)blockIdx.x*256 + threadIdx.x;   // < B*HW*64
  int c = (int)(t & 63);
  long pix = t >> 6;
  const float* ip = inp + pix*4;
  const float* wr = enc_w + c*5;
  float acc = enc_b[c] + ip[0]*wr[0] + ip[1]*wr[1] + ip[2]*wr[2] + ip[3]*wr[3] + g[pix]*wr[4];
  x[t] = (f16_t)acc;
}

// ---------------- forward DFT along w: fft1[b,h,ky,c] -----------------------
__global__ __launch_bounds__(256) void k_dft_w(const f16_t* __restrict__ x,
      const float4* __restrict__ twf4, float2* __restrict__ fft1){
  __shared__ float4 tw[1536];                      // [w][6]
  for (int f = threadIdx.x; f < 1536; f += 256) tw[f] = twf4[f];
  __syncthreads();
  int wave = threadIdx.x >> 6, lane = threadIdx.x & 63;
  long row = (long)blockIdx.x*4 + wave;            // b*H + h
  const f16_t* xr = x + row*16384 + lane;
  float ar[12], ai[12];
  #pragma unroll
  for (int k = 0; k < 12; k++){ ar[k] = 0.f; ai[k] = 0.f; }
  for (int w = 0; w < 256; w++){
    float xv = (float)xr[(long)w*64];
    const float4* t = &tw[w*6];
    #pragma unroll
    for (int k = 0; k < 6; k++){
      float4 tv = t[k];
      ar[2*k]   += xv*tv.x;  ai[2*k]   += xv*tv.y;
      ar[2*k+1] += xv*tv.z;  ai[2*k+1] += xv*tv.w;
    }
  }
  float2* op = fft1 + row*768 + lane;
  #pragma unroll
  for (int ky = 0; ky < 12; ky++) op[ky*64] = make_float2(ar[ky], ai[ky]);
}

// ------- forward DFT along h, tiled: block=(b,ky,jhalf), 768 blocks ---------
__global__ __launch_bounds__(256) void k_dft_h(const float2* __restrict__ fft1,
      const float2* __restrict__ thf, float2* __restrict__ xft){
  __shared__ float2 th[3072];                      // [h][24]
  __shared__ float2 xch[2048];                     // [32 h][64 c]
  int tid = threadIdx.x;
  for (int f = tid; f < 3072; f += 256) th[f] = thf[f];
  int blk = blockIdx.x;                            // < 768
  int b = blk / 24, r = blk % 24;
  int ky = r % 12, jh = r / 12;                    // j half: [jh*12, jh*12+12)
  int wv = tid >> 6, lane = tid & 63;
  float2 acc[3];
  #pragma unroll
  for (int q = 0; q < 3; q++) acc[q] = make_float2(0.f, 0.f);
  long base = (long)b*98304 + ky*64;
  for (int ch = 0; ch < 4; ch++){
    __syncthreads();
    for (int f = tid; f < 2048; f += 256){
      int hh = f >> 6, c = f & 63;
      xch[f] = fft1[base + (long)(ch*32 + hh)*768 + c];
    }
    __syncthreads();
    for (int hh = 0; hh < 32; hh++){
      float2 v = xch[hh*64 + lane];
      int hg = ch*32 + hh;
      #pragma unroll
      for (int q = 0; q < 3; q++){
        float2 t = th[hg*24 + jh*12 + q*4 + wv];
        acc[q].x += t.x*v.x - t.y*v.y;
        acc[q].y += t.x*v.y + t.y*v.x;
      }
    }
  }
  #pragma unroll
  for (int q = 0; q < 3; q++){
    int j = jh*12 + q*4 + wv;
    xft[((long)b*288 + j*12 + ky)*64 + lane] = acc[q];
  }
}

// -------- mode mixing IN PLACE (coalesced weights), 576 blocks --------------
__global__ __launch_bounds__(256) void k_mix(const float2* __restrict__ wmix,
      int layer, float2* __restrict__ xft){
  __shared__ float2 wl[4096];                      // [i][o]
  int jk = blockIdx.x >> 1;
  int bh2 = blockIdx.x & 1;
  int j = jk / 12, ky = jk % 12;
  const float2* wsrc = wmix + ((long)layer*288 + jk)*4096;
  for (int f = threadIdx.x; f < 4096; f += 256) wl[f] = wsrc[f];
  __syncthreads();
  int wave = threadIdx.x >> 6, lane = threadIdx.x & 63;
  for (int b = bh2*16 + wave; b < bh2*16 + 16; b += 4){
    long base = ((long)b*288 + j*12 + ky)*64;
    float2 mine = xft[base + lane];
    float re = 0.f, im = 0.f;
    #pragma unroll 8
    for (int i = 0; i < 64; i++){
      float vr = __shfl(mine.x, i);
      float vi = __shfl(mine.y, i);
      float2 ww = wl[i*64 + lane];
      re += vr*ww.x - vi*ww.y;
      im += vr*ww.y + vi*ww.x;
    }
    xft[base + lane] = make_float2(re, im);
  }
}

// ------- inverse DFT along h, tiled: block=(b,ky,hhalf), 768 blocks ---------
__global__ __launch_bounds__(256) void k_ifft_h(const float2* __restrict__ c3,
      const float2* __restrict__ thi, float2* __restrict__ zi){
  __shared__ float2 th[3072];                      // [h][24]
  int tid = threadIdx.x;
  for (int f = tid; f < 3072; f += 256) th[f] = thi[f];
  int blk = blockIdx.x;                            // < 768
  int b = blk / 24, r = blk % 24;
  int ky = r % 12, hh2 = r / 12;                   // h half: [hh2*64, hh2*64+64)
  int wv = tid >> 6, lane = tid & 63;
  float2 cr[24];
  const float2* src = c3 + (long)b*18432 + ky*64 + lane;
  #pragma unroll
  for (int j = 0; j < 24; j++) cr[j] = src[(long)j*768];
  __syncthreads();
  for (int q = 0; q < 16; q++){
    int h = hh2*64 + q*4 + wv;
    float re = 0.f, im = 0.f;
    #pragma unroll
    for (int j = 0; j < 24; j++){
      float2 t = th[h*24 + j];
      re += t.x*cr[j].x - t.y*cr[j].y;
      im += t.x*cr[j].y + t.y*cr[j].x;
    }
    zi[((long)b*128 + h)*768 + ky*64 + lane] = make_float2(re, im);
  }
}

// ------- MFMA: inverse-w + channel skip + bias + (gelu), in place on x ------
__global__ __launch_bounds__(256) void k_iw_mfma(f16_t* __restrict__ x,
      const float2* __restrict__ zi, const float* __restrict__ ws_w,
      const float* __restrict__ ws_b, const f16_t* __restrict__ twzh,
      int layer, int act){
  __shared__ __align__(16) char sm[52736];
  f16_t* A  = (f16_t*)sm;                   // [128][136]; reused as Ob [128][72]
  f16_t* Bm = (f16_t*)(sm + 34816);         // [64][136]
  float* sb = (float*)(sm + 52224);         // [64]
  f16_t* Ob = (f16_t*)sm;
  int tid = threadIdx.x;
  int blk = blockIdx.x;
  int half = blk & 1;
  long bh = blk >> 1;                       // b*128 + h
  int w0 = half*128;
  const f16_t* xrow = x + (bh*256 + w0)*64;
  for (int f = tid; f < 1024; f += 256){    // x part, 16B copies
    int px = f >> 3, c8 = (f & 7)*8;
    *(float4*)((char*)A + (px*136 + c8)*2) = *(const float4*)(xrow + px*64 + c8);
  }
  for (int f = tid; f < 3072; f += 256){    // twz part (duplicated hi/lo)
    int px = f/24, k = f%24;
    f16_t v = twzh[(w0+px)*32 + k];
    A[px*136 + 64 + k] = v;
    A[px*136 + 88 + k] = v;
  }
  for (int f = tid; f < 3072; f += 256){    // A zero pad k=112..135
    int px = f/24, k = f%24;
    A[px*136 + 112 + k] = (f16_t)0.f;
  }
  const float* wsl = ws_w + (long)layer*4096;
  for (int f = tid; f < 1024; f += 256){    // B ws part
    int o = f >> 4, c4 = f & 15;
    float4 v = *(const float4*)(wsl + o*64 + c4*4);
    f16_t* d = Bm + o*136 + c4*4;
    d[0]=(f16_t)v.x; d[1]=(f16_t)v.y; d[2]=(f16_t)v.z; d[3]=(f16_t)v.w;
  }
  const float2* zrow = zi + bh*768;
  for (int f = tid; f < 768; f += 256){     // B z hi/lo
    int o = f & 63, ky = f >> 6;
    float2 v = zrow[ky*64 + o];
    f16_t hr = (f16_t)v.x; f16_t hi_ = (f16_t)v.y;
    Bm[o*136 + 64 + ky] = hr;
    Bm[o*136 + 76 + ky] = hi_;
    Bm[o*136 + 88 + ky] = (f16_t)(v.x - (float)hr);
    Bm[o*136 +100 + ky] = (f16_t)(v.y - (float)hi_);
  }
  for (int f = tid; f < 1536; f += 256){    // B zero pad
    int o = f/24, k = f%24;
    Bm[o*136 + 112 + k] = (f16_t)0.f;
  }
  if (tid < 64) sb[tid] = ws_b[layer*64 + tid];
  __syncthreads();
  int lane = tid & 63, wv = tid >> 6;
  int n15 = lane & 15, quad = lane >> 4;
  int n = wv*16 + n15;
  half8 bfr[4];
  #pragma unroll
  for (int kc = 0; kc < 4; kc++)
    bfr[kc] = *(const half8*)(Bm + n*136 + kc*32 + quad*8);
  floatx4 acc[8];
  #pragma unroll
  for (int mt = 0; mt < 8; mt++){
    floatx4 c = {0.f,0.f,0.f,0.f};
    #pragma unroll
    for (int kc = 0; kc < 4; kc++){
      half8 a = *(const half8*)(A + (mt*16 + n15)*136 + kc*32 + quad*8);
      c = __builtin_amdgcn_mfma_f32_16x16x32_f16(a, bfr[kc], c, 0, 0, 0);
    }
    acc[mt] = c;
  }
  float bias = sb[n];
  __syncthreads();                           // A reads done -> reuse as Ob
  #pragma unroll
  for (int mt = 0; mt < 8; mt++){
    #pragma unroll
    for (int r = 0; r < 4; r++){
      int m = mt*16 + quad*4 + r;
      float v = acc[mt][r] + bias;
      if (act) v = gelu_f(v);
      Ob[m*72 + n] = (f16_t)v;
    }
  }
  __syncthreads();
  f16_t* xo = x + (bh*256 + w0)*64;
  for (int f = tid; f < 1024; f += 256){     // vectorized write-back
    int px = f >> 3, c8 = (f & 7)*8;
    *(float4*)(xo + px*64 + c8) = *(const float4*)((char*)Ob + (px*72 + c8)*2);
  }
}

// ------- MFMA conv 3x3 (per-batch weights) + gelu + head, fused; 64-px tiles -
__global__ __launch_bounds__(256) void k_conv_head(const f16_t* __restrict__ x,
      const float* __restrict__ ext, const f16_t* __restrict__ wT,
      const float* __restrict__ tb, const f16_t* __restrict__ f1T,
      const float* __restrict__ f1_b, const f16_t* __restrict__ f2T,
      const float* __restrict__ f2_b, const f16_t* __restrict__ f3T,
      const float* __restrict__ f3_b, float* __restrict__ out){
  __shared__ __align__(16) char sm[37632];
  f16_t* hf   = (f16_t*)sm;                 // [64][72]   9216
  f16_t* z1   = (f16_t*)(sm + 9216);        // [64][136]  17408
  f16_t* z2   = (f16_t*)(sm + 26624);       // [64][72]   9216
  float* tbs  = (float*)(sm + 35840);       // 64
  float* f1bs = (float*)(sm + 36096);       // 128
  float* f2bs = (float*)(sm + 36608);       // 64
  f16_t* f3s  = (f16_t*)(sm + 36864);       // 128 f16
  float* f3bs = (float*)(sm + 37120);       // 2
  f16_t* xt   = (f16_t*)sm;                 // [3][66][72] = 28512 B (conv phase)

  int tid = threadIdx.x;
  int blk = blockIdx.x;
  int wc = blk & 3, h = (blk >> 2) & 127, b = blk >> 9;
  int w0 = wc*64;
  int t_idx = (int)ext[b*6+3] - 5;

  if (tid < 64) tbs[tid] = tb[t_idx*64 + tid];
  else if (tid < 192) f1bs[tid-64] = f1_b[tid-64];
  else f2bs[tid-192] = f2_b[tid-192];
  if (tid < 128) f3s[tid] = f3T[tid];
  if (tid < 2) f3bs[tid] = f3_b[tid];

  for (int f = tid; f < 3168; f += 256){    // xt: 3 rows x 66 px x 64 c
    int c4 = f & 15, r = f >> 4;
    int dy = r/66, pxl = r%66;
    int hh = h - 1 + dy, wg = w0 - 1 + pxl;
    ushort4 v = {0,0,0,0};
    if (hh >= 0 && hh < HH_ && wg >= 0 && wg < WW_)
      v = *(const ushort4*)(x + (((long)b*HH_ + hh)*WW_ + wg)*64 + c4*4);
    *(ushort4*)((unsigned short*)xt + (dy*66 + pxl)*72 + c4*4) = v;
  }
  __syncthreads();

  int lane = tid & 63, wv = tid >> 6;
  int n15 = lane & 15, quad = lane >> 4;

  floatx4 acc[4];
  #pragma unroll
  for (int mt = 0; mt < 4; mt++) acc[mt] = (floatx4){0.f,0.f,0.f,0.f};
  const f16_t* wTt = wT + (long)t_idx*36864;
  for (int tap = 0; tap < 9; tap++){
    int dy = tap/3, dx = tap%3;
    const f16_t* wrow = wTt + (tap*64 + wv*16 + n15)*64;
    #pragma unroll
    for (int kc = 0; kc < 2; kc++){
      half8 bfrag = *(const half8*)(wrow + kc*32 + quad*8);
      #pragma unroll
      for (int mt = 0; mt < 4; mt++){
        int p = mt*16 + n15 + dx;
        half8 a = *(const half8*)(xt + (dy*66 + p)*72 + kc*32 + quad*8);
        acc[mt] = __builtin_amdgcn_mfma_f32_16x16x32_f16(a, bfrag, acc[mt], 0,0,0);
      }
    }
  }
  __syncthreads();                           // xt dead
  {
    int n = wv*16 + n15;
    float bias = tbs[n];
    #pragma unroll
    for (int mt = 0; mt < 4; mt++){
      #pragma unroll
      for (int r = 0; r < 4; r++){
        int m = mt*16 + quad*4 + r;
        hf[m*72 + n] = (f16_t)gelu_f(acc[mt][r] + bias);
      }
    }
  }
  __syncthreads();
  // z1 = gelu(hf . f1^T + f1_b): M=64 N=128 K=64
  #pragma unroll
  for (int nt = 0; nt < 2; nt++){
    int n = wv*32 + nt*16 + n15;
    float bias = f1bs[n];
    half8 bf0 = *(const half8*)(f1T + n*64 + quad*8);
    half8 bf1 = *(const half8*)(f1T + n*64 + 32 + quad*8);
    #pragma unroll
    for (int mt = 0; mt < 4; mt++){
      floatx4 c = {0.f,0.f,0.f,0.f};
      half8 a0 = *(const half8*)(hf + (mt*16 + n15)*72 + quad*8);
      half8 a1 = *(const half8*)(hf + (mt*16 + n15)*72 + 32 + quad*8);
      c = __builtin_amdgcn_mfma_f32_16x16x32_f16(a0, bf0, c, 0,0,0);
      c = __builtin_amdgcn_mfma_f32_16x16x32_f16(a1, bf1, c, 0,0,0);
      #pragma unroll
      for (int r = 0; r < 4; r++){
        int m = mt*16 + quad*4 + r;
        z1[m*136 + n] = (f16_t)gelu_f(c[r] + bias);
      }
    }
  }
  __syncthreads();
  // z2 = gelu(z1 . f2^T + f2_b): M=64 N=64 K=128
  {
    int n = wv*16 + n15;
    float bias = f2bs[n];
    half8 bf[4];
    #pragma unroll
    for (int kc = 0; kc < 4; kc++)
      bf[kc] = *(const half8*)(f2T + n*128 + kc*32 + quad*8);
    #pragma unroll
    for (int mt = 0; mt < 4; mt++){
      floatx4 c = {0.f,0.f,0.f,0.f};
      #pragma unroll
      for (int kc = 0; kc < 4; kc++){
        half8 a = *(const half8*)(z1 + (mt*16 + n15)*136 + kc*32 + quad*8);
        c = __builtin_amdgcn_mfma_f32_16x16x32_f16(a, bf[kc], c, 0,0,0);
      }
      #pragma unroll
      for (int r = 0; r < 4; r++){
        int m = mt*16 + quad*4 + r;
        z2[m*72 + n] = (f16_t)gelu_f(c[r] + bias);
      }
    }
  }
  __syncthreads();
  // f3: out[px][0..1]
  if (tid < 128){
    int px = tid >> 1, oo = tid & 1;
    const f16_t* zr = z2 + px*72;
    const f16_t* fr = f3s + oo*64;
    float a = f3bs[oo];
    #pragma unroll
    for (int g = 0; g < 8; g++){
      half8 zv = *(const half8*)(zr + g*8);
      half8 wv2 = *(const half8*)(fr + g*8);
      #pragma unroll
      for (int q = 0; q < 8; q++) a += (float)zv[q]*(float)wv2[q];
    }
    out[(((long)b*HH_ + h)*WW_ + w0 + px)*2 + oo] = a;
  }
}

extern "C" void kernel_launch(void* const* d_in, const int* in_sizes, int n_in,
                              void* d_out, int out_size, void* d_ws, size_t ws_size,
                              hipStream_t stream){
  const float* inp     = (const float*)d_in[0];
  const float* ext     = (const float*)d_in[1];
  const float* enc_w   = (const float*)d_in[2];
  const float* enc_b   = (const float*)d_in[3];
  const float* w1r     = (const float*)d_in[4];
  const float* w1i     = (const float*)d_in[5];
  const float* w2r     = (const float*)d_in[6];
  const float* w2i     = (const float*)d_in[7];
  const float* ws_w    = (const float*)d_in[8];
  const float* ws_b    = (const float*)d_in[9];
  const float* day_emb = (const float*)d_in[10];
  const float* hour_emb= (const float*)d_in[11];
  const float* e1_w    = (const float*)d_in[12];
  const float* e1_b    = (const float*)d_in[13];
  const float* e2_w    = (const float*)d_in[14];
  const float* e2_b    = (const float*)d_in[15];
  const float* tw      = (const float*)d_in[16];
  const float* tb      = (const float*)d_in[17];
  const float* f1_w    = (const float*)d_in[18];
  const float* f1_b    = (const float*)d_in[19];
  const float* f2_w    = (const float*)d_in[20];
  const float* f2_b    = (const float*)d_in[21];
  const float* f3_w    = (const float*)d_in[22];
  const float* f3_b    = (const float*)d_in[23];
  float* outp = (float*)d_out;

  const size_t need = 207208704;
  if (ws_size < need){
    k_diag<<<dim3(1), dim3(64), 0, stream>>>(outp, (float)(ws_size >> 20));
    return;
  }
  char* p = (char*)d_ws;
  f16_t*  x    = (f16_t*)(p);                    // 134217728 B
  float2* fft1 = (float2*)(p + 134217728);       // 25165824 B (zi alias)
  float2* xft  = (float2*)(p + 159383552);       // 4718592 B
  float*  g    = (float*)(p + 164102144);        // 4194304 B
  float*  g1   = (float*)(p + 168296448);        // 8192 B
  float2* twf  = (float2*)(p + 168304640);       // 24576 B
  float2* thf  = (float2*)(p + 168329216);       // 24576 B
  float2* thi  = (float2*)(p + 168353792);       // 24576 B
  f16_t*  twzh = (f16_t*)(p + 168378368);        // 16384 B
  f16_t*  wT   = (f16_t*)(p + 168394752);        // 1032192 B
  f16_t*  f1T  = (f16_t*)(p + 169426944);        // 16384 B
  f16_t*  f2T  = (f16_t*)(p + 169443328);        // 16384 B
  f16_t*  f3T  = (f16_t*)(p + 169459712);        // 256 B
  float2* wmix = (float2*)(p + 169459968);       // 37748736 B
  float2* zi   = fft1;

  k_tables<<<dim3(48), dim3(256), 0, stream>>>(twf, thf, thi, twzh);
  k_wprep<<<dim3(56), dim3(256), 0, stream>>>(tw, wT);
  k_wprep2<<<dim3(65), dim3(256), 0, stream>>>(f1_w, f2_w, f3_w, f1T, f2T, f3T);
  k_mixprep<<<dim3(768), dim3(256), 0, stream>>>(w1r, w1i, w2r, w2i, wmix);
  k_ext<<<dim3(32), dim3(64), 0, stream>>>(ext, day_emb, hour_emb, e1_w, e1_b, g1);
  k_g<<<dim3(128, 32), dim3(256), 0, stream>>>(g1, e2_w, e2_b, g);
  k_enc<<<dim3(262144), dim3(256), 0, stream>>>(inp, g, enc_w, enc_b, x);
  for (int l = 0; l < 4; l++){
    k_dft_w<<<dim3(1024), dim3(256), 0, stream>>>(x, (const float4*)twf, fft1);
    k_dft_h<<<dim3(768), dim3(256), 0, stream>>>(fft1, thf, xft);
    k_mix<<<dim3(576), dim3(256), 0, stream>>>(wmix, l, xft);
    k_ifft_h<<<dim3(768), dim3(256), 0, stream>>>(xft, thi, zi);
    k_iw_mfma<<<dim3(8192), dim3(256), 0, stream>>>(x, zi, ws_w, ws_b, twzh,
                                                    l, (l < 3) ? 1 : 0);
  }
  k_conv_head<<<dim3(16384), dim3(256), 0, stream>>>(x, ext, wT, tb,
                     f1T, f1_b, f2T, f2_b, f3T, f3_b, outp);
}